// Round 3
// baseline (581.396 us; speedup 1.0000x reference)
//
#include <hip/hip_runtime.h>
#include <hip/hip_bf16.h>
#include <math.h>

// ============================================================================
// EquiGroupSamplingC8 (f32 I/O confirmed by runtime sniff; bf16 path retained).
// R3: MFMA x_c8, BM64/BN128 GEMMs, restructured assemble, 7 dispatches.
// ============================================================================

typedef __attribute__((ext_vector_type(8))) short bf16x8;
typedef __attribute__((ext_vector_type(4))) float f32x4;

__device__ const int c_offs[8] = {0, 1, 10, 35, 84, 165, 286, 455};

struct SetupArgs {
  double angA[16];              // 2*pi*k/16 (alpha and gamma grid)
  double angB[8];               // arccos(GL8 nodes)
  double c8a[8], c8b[8], c8g[8];
};
struct QWArgs { double wb[8]; };
struct W2Ptrs { const void* p[7]; };

__device__ __forceinline__ float bf2f(unsigned short u) {
  union { unsigned int i; float f; } v; v.i = ((unsigned int)u) << 16; return v.f;
}
__device__ __forceinline__ unsigned short f2bf(float f) {
  union { float f; unsigned int i; } v; v.f = f;
  unsigned int r = v.i + 0x7fffu + ((v.i >> 16) & 1u);
  return (unsigned short)(r >> 16);
}
__device__ __forceinline__ float in_val(const void* p, size_t i, int isf) {
  return isf ? ((const float*)p)[i] : bf2f(((const unsigned short*)p)[i]);
}
__device__ __forceinline__ void gl_lds16(const void* g, void* lds) {
  __builtin_amdgcn_global_load_lds(
      (const __attribute__((address_space(1))) unsigned int*)g,
      (__attribute__((address_space(3))) unsigned int*)lds, 16, 0, 0);
}

// ---------------------------------------------------------------------------
// K1: exp matrices. blocks [0,336) = 7 l * 48 items; block 336 = dtype sniff.
// items: [0,16) grid-alpha/gamma (axis1), [16,24) grid-beta (axis0),
//        [24,32) c8 alpha (axis1), [32,40) c8 beta (axis0), [40,48) c8 gamma (axis1)
// ---------------------------------------------------------------------------
__global__ __launch_bounds__(64) void k_exps(SetupArgs args, double* exps,
                                             const void* x, int* flag) {
  __shared__ double Qr[169], Qi[169], G[169], Bm[169], R[169], T[169];
  __shared__ double snorm;
  __shared__ int cnt;
  int tid = threadIdx.x;

  if (blockIdx.x == 336) {           // dtype sniff: f32 N(0,1) magnitude band
    if (tid == 0) cnt = 0;
    __syncthreads();
    float v = ((const float*)x)[tid];
    float a = fabsf(v);
    int ok = (v == v) && (a > 9.0949470e-13f) && (a < 1.0995116e12f);
    atomicAdd(&cnt, ok);
    __syncthreads();
    if (tid == 0) *flag = (cnt >= 32) ? 1 : 0;
    return;
  }

  int l = blockIdx.x / 48, item = blockIdx.x % 48;
  int n = 2 * l + 1;

  for (int e = tid; e < n * n; e += 64) { Qr[e] = 0.0; Qi[e] = 0.0; }
  __syncthreads();
  if (tid == 0) {
    const double is2 = 0.70710678118654752440;
    for (int m = -l; m <= l; m++) {
      int r = l + m;
      if (m < 0) {
        Qr[r * n + (l - m)] = is2;
        Qi[r * n + (l + m)] = -is2;
      } else if (m == 0) {
        Qr[l * n + l] = 1.0;
      } else {
        double s = (m & 1) ? -1.0 : 1.0;
        Qr[r * n + (l + m)] = s * is2;
        Qi[r * n + (l - m)] = s * is2;
      }
    }
  }
  __syncthreads();
  { // multiply by (-1j)^l
    int lm = l & 3;
    double pr = (lm == 0) ? 1.0 : (lm == 2 ? -1.0 : 0.0);
    double pi = (lm == 1) ? -1.0 : (lm == 3 ? 1.0 : 0.0);
    for (int e = tid; e < n * n; e += 64) {
      double qr = Qr[e], qi = Qi[e];
      Qr[e] = qr * pr - qi * pi;
      Qi[e] = qr * pi + qi * pr;
    }
  }
  __syncthreads();

  double t; int axis;
  if (item < 16)      { t = args.angA[item];      axis = 1; }
  else if (item < 24) { t = args.angB[item - 16]; axis = 0; }
  else if (item < 32) { t = args.c8a[item - 24];  axis = 1; }
  else if (item < 40) { t = args.c8b[item - 32];  axis = 0; }
  else                { t = args.c8g[item - 40];  axis = 1; }

  double jj = (double)l;
  for (int e = tid; e < n * n; e += 64) {
    int r = e / n, c = e % n;
    double accr = 0.0;
    if (axis == 1) {
      for (int p = 0; p < n; p++) {
        double mp = (double)(p - l);
        double ar = Qr[p * n + r], ai = -Qi[p * n + r];
        double br = Qr[p * n + c], bi = Qi[p * n + c];
        accr += -mp * (ar * bi + ai * br);
      }
    } else {
      for (int p = 0; p < n; p++) {
        double xr = 0.0, xi = 0.0;
        if (p > 0) {
          double m = (double)(p - 1 - l);
          double v = -0.5 * sqrt(jj * (jj + 1.0) - m * (m + 1.0));
          xr += v * Qr[(p - 1) * n + c]; xi += v * Qi[(p - 1) * n + c];
        }
        if (p < n - 1) {
          double m = (double)(p + 1 - l);
          double v = 0.5 * sqrt(jj * (jj + 1.0) - m * (m - 1.0));
          xr += v * Qr[(p + 1) * n + c]; xi += v * Qi[(p + 1) * n + c];
        }
        double ar = Qr[p * n + r], ai = -Qi[p * n + r];
        accr += ar * xr - ai * xi;
      }
    }
    G[e] = accr;
  }
  __syncthreads();
  for (int e = tid; e < n * n; e += 64) Bm[e] = t * G[e];
  __syncthreads();
  if (tid == 0) {
    double mx = 0.0;
    for (int r = 0; r < n; r++) {
      double s = 0.0;
      for (int c = 0; c < n; c++) s += fabs(Bm[r * n + c]);
      if (s > mx) mx = s;
    }
    int s = 0;
    while (mx > 0.5 && s < 48) { mx *= 0.5; s++; }
    snorm = (double)s;
  }
  __syncthreads();
  int sq = (int)snorm;
  double sc = 1.0;
  for (int i = 0; i < sq; i++) sc *= 0.5;
  for (int e = tid; e < n * n; e += 64) Bm[e] *= sc;
  __syncthreads();
  for (int e = tid; e < n * n; e += 64) {
    int r = e / n, c = e % n;
    R[e] = Bm[e] / 16.0 + ((r == c) ? 1.0 : 0.0);
  }
  __syncthreads();
  for (int k = 15; k >= 1; k--) {
    for (int e = tid; e < n * n; e += 64) {
      int r = e / n, c = e % n;
      double acc = 0.0;
      for (int p = 0; p < n; p++) acc += Bm[r * n + p] * R[p * n + c];
      T[e] = acc / (double)k + ((r == c) ? 1.0 : 0.0);
    }
    __syncthreads();
    for (int e = tid; e < n * n; e += 64) R[e] = T[e];
    __syncthreads();
  }
  for (int i = 0; i < sq; i++) {
    for (int e = tid; e < n * n; e += 64) {
      int r = e / n, c = e % n;
      double acc = 0.0;
      for (int p = 0; p < n; p++) acc += R[r * n + p] * R[p * n + c];
      T[e] = acc;
    }
    __syncthreads();
    for (int e = tid; e < n * n; e += 64) R[e] = T[e];
    __syncthreads();
  }
  double* out = exps + (size_t)blockIdx.x * 169;
  for (int e = tid; e < n * n; e += 64) out[e] = R[e];
}

// ---------------------------------------------------------------------------
// K2: assemble. blocks [0,896) = (l,a,b), loop over 16 c: dwt/dint;
// [896,952) = (l,ci) c8 -> c8w f32 + c8bT bf16[16][512];
// [952,2232) = feat (proj_1) work.
// ---------------------------------------------------------------------------
__global__ __launch_bounds__(64) void k_assemble(const double* exps, QWArgs qw,
                                                 unsigned short* dwt, float* dint,
                                                 float* c8w, unsigned short* c8bT,
                                                 const void* traj, const void* w1l0,
                                                 const void* w1l1, float* feat,
                                                 const int* flag) {
  __shared__ double Ea[169], Eb[169], Ec[169], T1[169];
  int tid = threadIdx.x;
  int bx = blockIdx.x;

  if (bx >= 952) {                    // ---- feat (proj_1) ----
    int isf = __builtin_amdgcn_readfirstlane(flag[0]);
    int idx = (bx - 952) * 64 + tid;
    if (idx >= 512 * 160) return;
    int bt = idx / 160, rem = idx % 160;
    int c = rem / 10, i = rem % 10;
    float v;
    if (i == 0) {
      v = in_val(traj, bt * 10 + 9, isf) * in_val(w1l0, c, isf);
    } else {
      int ii = i - 1, w = ii / 3, m = ii % 3;
      float acc = 0.0f;
      for (int u = 0; u < 3; u++)
        acc += in_val(traj, bt * 10 + 3 * u + m, isf) *
               in_val(w1l1, c * 9 + u * 3 + w, isf);
      v = acc * 0.57735026918962576f;
    }
    feat[idx] = v;
    return;
  }

  if (bx >= 896) {                    // ---- C8 points ----
    int idx = bx - 896;
    int l = idx / 8, ci = idx % 8;
    int d = 2 * l + 1;
    const double* pa = exps + (size_t)(l * 48 + 24 + ci) * 169;
    const double* pb = exps + (size_t)(l * 48 + 32 + ci) * 169;
    const double* pc = exps + (size_t)(l * 48 + 40 + ci) * 169;
    for (int e = tid; e < d * d; e += 64) { Ea[e] = pa[e]; Eb[e] = pb[e]; Ec[e] = pc[e]; }
    __syncthreads();
    for (int e = tid; e < d * d; e += 64) {
      int r = e / d, c = e % d; double acc = 0.0;
      for (int p = 0; p < d; p++) acc += Ea[r * d + p] * Eb[p * d + c];
      T1[e] = acc;
    }
    __syncthreads();
    double scale = sqrt((double)(2 * l + 1));
    for (int e = tid; e < d * d; e += 64) {
      int r = e / d, c = e % d; double acc = 0.0;
      for (int p = 0; p < d; p++) acc += T1[r * d + p] * Ec[p * d + c];
      float v = (float)(scale * acc);
      c8w[ci * 512 + c_offs[l] + e] = v;
      c8bT[ci * 512 + c_offs[l] + e] = f2bf(v);
    }
    if (l == 0) {
      for (int jz = 455 + tid; jz < 512; jz += 64) {
        c8w[ci * 512 + jz] = 0.0f;
        c8bT[ci * 512 + jz] = 0;
      }
      for (int jz = tid; jz < 512; jz += 64)
        c8bT[(8 + ci) * 512 + jz] = 0;     // unused MFMA cols
    }
    return;
  }

  // ---- grid (l, a, b), loop c ----
  int l = bx / 128, ab = bx % 128;
  int a = ab >> 3, b = ab & 7;
  int d = 2 * l + 1;
  const double* pa = exps + (size_t)(l * 48 + a) * 169;
  const double* pb = exps + (size_t)(l * 48 + 16 + b) * 169;
  for (int e = tid; e < d * d; e += 64) { Ea[e] = pa[e]; Eb[e] = pb[e]; }
  __syncthreads();
  for (int e = tid; e < d * d; e += 64) {
    int r = e / d, c = e % d; double acc = 0.0;
    for (int p = 0; p < d; p++) acc += Ea[r * d + p] * Eb[p * d + c];
    T1[e] = acc;
  }
  double scale = sqrt((double)(2 * l + 1));
  double qwv = qw.wb[b] * (1.0 / 512.0);
  const double* ctab = exps + (size_t)(l * 48) * 169;   // items [0,16) = gamma
  for (int cc = 0; cc < 16; cc++) {
    __syncthreads();
    const double* pc = ctab + (size_t)cc * 169;
    for (int e = tid; e < d * d; e += 64) Ec[e] = pc[e];
    __syncthreads();
    int g = a * 128 + b * 16 + cc;
    for (int e = tid; e < d * d; e += 64) {
      int r = e / d, c = e % d; double acc = 0.0;
      for (int p = 0; p < d; p++) acc += T1[r * d + p] * Ec[p * d + c];
      int j = c_offs[l] + e;
      dwt[(size_t)j * 2048 + g] = f2bf((float)(scale * acc * qwv));
      if (l == 1) dint[(size_t)(1 + e) * 2048 + g] = (float)(scale * acc);
      if (l == 0 && e == 0) dint[g] = (float)(scale * acc);
    }
    if (l == 0) {
      for (int jz = 455 + tid; jz < 512; jz += 64)
        dwt[(size_t)jz * 2048 + g] = 0;
    }
  }
}

// ---------------------------------------------------------------------------
// K3: sig [8192][2048] bf16 = relu(feat @ D_IN^T) * sqrt(2)
// ---------------------------------------------------------------------------
__global__ __launch_bounds__(256) void k_sig(const float* feat, const float* dint,
                                             unsigned short* sig) {
  int bi = blockIdx.x >> 3;
  int g = ((blockIdx.x & 7) << 8) + threadIdx.x;
  float din[10];
#pragma unroll
  for (int i = 0; i < 10; i++) din[i] = dint[(size_t)i * 2048 + g];
  const float* fr = feat + bi * 160;
  for (int cc = 0; cc < 16; cc++) {
    float acc = 0.0f;
#pragma unroll
    for (int i = 0; i < 10; i++) acc += fr[cc * 10 + i] * din[i];
    acc = fmaxf(acc, 0.0f) * 1.41421356237309505f;
    sig[(size_t)(bi * 16 + cc) * 2048 + g] = f2bf(acc);
  }
}

// ---------------------------------------------------------------------------
// K4: E_T [512][8192] bf16: row n=g*8+i, col k=f*512+jj
// ---------------------------------------------------------------------------
__global__ __launch_bounds__(256) void k_ebuild(W2Ptrs w2, const float* c8w,
                                                unsigned short* et, const int* flag) {
  int isf = __builtin_amdgcn_readfirstlane(flag[0]);
  int idx = blockIdx.x * 256 + threadIdx.x;     // 512*16*512
  int n = idx >> 13;
  int rest = idx & 8191;
  int f = rest >> 9, jj = rest & 511;
  size_t oaddr = (size_t)n * 8192 + f * 512 + jj;
  if (jj >= 455) { et[oaddr] = 0; return; }
  int l = 0;
  while (jj >= c_offs[l + 1]) l++;
  int d = 2 * l + 1;
  int rloc = jj - c_offs[l];
  int u = rloc / d, m = rloc % d;
  int g = n >> 3, i = n & 7;
  const void* wp = w2.p[l];
  float acc = 0.0f;
  for (int w = 0; w < d; w++) {
    float wv = in_val(wp, ((size_t)(f * 64 + g) * d + u) * d + w, isf);
    acc += wv * c8w[i * 512 + c_offs[l] + w * d + m];
  }
  acc *= rsqrtf((float)(16 * d));
  et[oaddr] = f2bf(acc);
}

// ---------------------------------------------------------------------------
// K5: GEMM2: f2[8192][512] = sig[8192][2048] @ dwt^T. BM=64 BN=128 BK=32.
// grid 512 = 128 mt x 4 nt; 256 thr, 4 waves 2x2 (wave tile 32x64).
// ---------------------------------------------------------------------------
__global__ __launch_bounds__(256) void k_gemm2(const unsigned short* A,
                                               const unsigned short* B,
                                               unsigned short* C) {
  __shared__ __align__(16) unsigned short As[64 * 32];
  __shared__ __align__(16) unsigned short Bs[128 * 32];
  int tid = threadIdx.x;
  int lane = tid & 63, wid = tid >> 6;
  int mt = blockIdx.x >> 2, nt = blockIdx.x & 3;
  int m0 = mt * 64, n0 = nt * 128;
  int wm = wid >> 1, wn = wid & 1;
  f32x4 acc[2][4];
#pragma unroll
  for (int a = 0; a < 2; a++)
#pragma unroll
    for (int b = 0; b < 4; b++) acc[a][b] = (f32x4){0.f, 0.f, 0.f, 0.f};
  int c0 = tid;
  int ar = c0 >> 2, ak = (c0 & 3) * 8;
  const unsigned short* Abase = A + (size_t)m0 * 2048;
  const unsigned short* Bbase = B + (size_t)n0 * 2048;
  int row = lane & 15, kq = (lane >> 4) * 8;
  for (int kt = 0; kt < 64; kt++) {
    int k0 = kt * 32;
    gl_lds16(Abase + (size_t)ar * 2048 + k0 + ak, &As[wid * 512]);
    gl_lds16(Bbase + (size_t)ar * 2048 + k0 + ak, &Bs[wid * 512]);
    gl_lds16(Bbase + (size_t)(ar + 64) * 2048 + k0 + ak, &Bs[2048 + wid * 512]);
    __syncthreads();
    bf16x8 af[2], bfr[4];
#pragma unroll
    for (int im = 0; im < 2; im++)
      af[im] = *(const bf16x8*)&As[(wm * 32 + im * 16 + row) * 32 + kq];
#pragma unroll
    for (int in = 0; in < 4; in++)
      bfr[in] = *(const bf16x8*)&Bs[(wn * 64 + in * 16 + row) * 32 + kq];
#pragma unroll
    for (int im = 0; im < 2; im++)
#pragma unroll
      for (int in = 0; in < 4; in++)
        acc[im][in] = __builtin_amdgcn_mfma_f32_16x16x32_bf16(af[im], bfr[in],
                                                              acc[im][in], 0, 0, 0);
    __syncthreads();
  }
  int col = lane & 15, rq = (lane >> 4) * 4;
#pragma unroll
  for (int im = 0; im < 2; im++)
#pragma unroll
    for (int in = 0; in < 4; in++)
#pragma unroll
      for (int r = 0; r < 4; r++) {
        int rr = m0 + wm * 32 + im * 16 + rq + r;
        int cc = n0 + wn * 64 + in * 16 + col;
        C[(size_t)rr * 512 + cc] = f2bf(acc[im][in][r]);
      }
}

// ---------------------------------------------------------------------------
// K6: GEMM3 split-K=8: Cp[kc][512][512] f32 = f2[512][8192] @ E (E_T staged)
// BM=64 BN=128, grid 256 = 8 kc x 8 mt x 4 nt, 32 K-steps each.
// ---------------------------------------------------------------------------
__global__ __launch_bounds__(256) void k_gemm3(const unsigned short* A,
                                               const unsigned short* B, float* Cp) {
  __shared__ __align__(16) unsigned short As[64 * 32];
  __shared__ __align__(16) unsigned short Bs[128 * 32];
  int tid = threadIdx.x, lane = tid & 63, wid = tid >> 6;
  int kc = blockIdx.x >> 5;
  int mt = (blockIdx.x >> 2) & 7, nt = blockIdx.x & 3;
  int m0 = mt * 64, n0 = nt * 128;
  int wm = wid >> 1, wn = wid & 1;
  f32x4 acc[2][4];
#pragma unroll
  for (int a = 0; a < 2; a++)
#pragma unroll
    for (int b = 0; b < 4; b++) acc[a][b] = (f32x4){0.f, 0.f, 0.f, 0.f};
  int c0 = tid;
  int ar = c0 >> 2, ak = (c0 & 3) * 8;
  const unsigned short* Abase = A + (size_t)m0 * 8192 + kc * 1024;
  const unsigned short* Bbase = B + (size_t)n0 * 8192 + kc * 1024;
  int row = lane & 15, kq = (lane >> 4) * 8;
  for (int kt = 0; kt < 32; kt++) {
    int k0 = kt * 32;
    gl_lds16(Abase + (size_t)ar * 8192 + k0 + ak, &As[wid * 512]);
    gl_lds16(Bbase + (size_t)ar * 8192 + k0 + ak, &Bs[wid * 512]);
    gl_lds16(Bbase + (size_t)(ar + 64) * 8192 + k0 + ak, &Bs[2048 + wid * 512]);
    __syncthreads();
    bf16x8 af[2], bfr[4];
#pragma unroll
    for (int im = 0; im < 2; im++)
      af[im] = *(const bf16x8*)&As[(wm * 32 + im * 16 + row) * 32 + kq];
#pragma unroll
    for (int in = 0; in < 4; in++)
      bfr[in] = *(const bf16x8*)&Bs[(wn * 64 + in * 16 + row) * 32 + kq];
#pragma unroll
    for (int im = 0; im < 2; im++)
#pragma unroll
      for (int in = 0; in < 4; in++)
        acc[im][in] = __builtin_amdgcn_mfma_f32_16x16x32_bf16(af[im], bfr[in],
                                                              acc[im][in], 0, 0, 0);
    __syncthreads();
  }
  int col = lane & 15, rq = (lane >> 4) * 4;
  float* out = Cp + (size_t)kc * 262144;
#pragma unroll
  for (int im = 0; im < 2; im++)
#pragma unroll
    for (int in = 0; in < 4; in++)
#pragma unroll
      for (int r = 0; r < 4; r++) {
        int rr = m0 + wm * 32 + im * 16 + rq + r;
        int cc = n0 + wn * 64 + in * 16 + col;
        out[(size_t)rr * 512 + cc] = acc[im][in][r];
      }
}

// ---------------------------------------------------------------------------
// K7: x_c8 via MFMA (blocks [0,4096)) + split-K reduce (blocks [4096,5120)).
// 64 threads/block. x-block: 16 rows staged to LDS f32 [16][484] (pad:
// bank stride 4), 15 x mfma_16x16x32_bf16 vs c8bT[16][512].
// ---------------------------------------------------------------------------
__global__ __launch_bounds__(64) void k_xc8red(const void* x, const unsigned short* c8bT,
                                               const float* Cp, void* dout,
                                               const int* flag) {
  __shared__ __align__(16) float xs[16 * 484];
  int tid = threadIdx.x;
  int isf = __builtin_amdgcn_readfirstlane(flag[0]);

  if (blockIdx.x >= 4096) {           // ---- split-K reduce -> traj_c8 ----
    int idx = (blockIdx.x - 4096) * 64 + tid;    // [0, 65536)
    const float4* c = (const float4*)Cp;
    float s0 = 0.f, s1 = 0.f, s2 = 0.f, s3 = 0.f;
#pragma unroll
    for (int p = 0; p < 8; p++) {
      float4 v = c[idx + p * 65536];
      s0 += v.x; s1 += v.y; s2 += v.z; s3 += v.w;
    }
    size_t base = 524288 + (size_t)idx * 4;
    if (isf) {
      float4 o; o.x = s0; o.y = s1; o.z = s2; o.w = s3;
      *(float4*)((float*)dout + base) = o;
    } else {
      unsigned int p0 = (unsigned int)f2bf(s0) | ((unsigned int)f2bf(s1) << 16);
      unsigned int p1 = (unsigned int)f2bf(s2) | ((unsigned int)f2bf(s3) << 16);
      uint2 pk; pk.x = p0; pk.y = p1;
      *(uint2*)((unsigned short*)dout + base) = pk;
    }
    return;
  }

  // ---- x_c8 ----
  int r0 = blockIdx.x * 16;
  int lane = tid;
  // B fragments (L2-hot)
  bf16x8 bf[15];
  int bbase = (lane & 15) * 512 + (lane >> 4) * 8;
#pragma unroll
  for (int s = 0; s < 15; s++)
    bf[s] = *(const bf16x8*)&c8bT[bbase + s * 32];
  // zero pad cols [455,480)
  for (int idx = tid; idx < 400; idx += 64) {
    int r = idx / 25, j = 455 + idx % 25;
    xs[r * 484 + j] = 0.0f;
  }
  // stage 16 rows
  const float* xf = (const float*)x;
  const unsigned short* xh = (const unsigned short*)x;
  if (isf) {
    for (int r = 0; r < 16; r++) {
      size_t rb = (size_t)(r0 + r) * 455;
      for (int j = tid; j < 455; j += 64) xs[r * 484 + j] = xf[rb + j];
    }
  } else {
    for (int r = 0; r < 16; r++) {
      size_t rb = (size_t)(r0 + r) * 455;
      for (int j = tid; j < 455; j += 64) xs[r * 484 + j] = bf2f(xh[rb + j]);
    }
  }
  __syncthreads();
  f32x4 acc = (f32x4){0.f, 0.f, 0.f, 0.f};
  int arow = (lane & 15) * 484 + (lane >> 4) * 8;
#pragma unroll
  for (int s = 0; s < 15; s++) {
    const float* p = &xs[arow + s * 32];
    float4 lo = *(const float4*)p;
    float4 hi = *(const float4*)(p + 4);
    union { bf16x8 v; unsigned short u[8]; } a;
    a.u[0] = f2bf(lo.x); a.u[1] = f2bf(lo.y); a.u[2] = f2bf(lo.z); a.u[3] = f2bf(lo.w);
    a.u[4] = f2bf(hi.x); a.u[5] = f2bf(hi.y); a.u[6] = f2bf(hi.z); a.u[7] = f2bf(hi.w);
    acc = __builtin_amdgcn_mfma_f32_16x16x32_bf16(a.v, bf[s], acc, 0, 0, 0);
  }
  int n = lane & 15;
  if (n < 8) {
    int rbase = r0 + (lane >> 4) * 4;
#pragma unroll
    for (int r = 0; r < 4; r++) {
      size_t o = (size_t)(rbase + r) * 8 + n;
      if (isf) ((float*)dout)[o] = acc[r];
      else     ((unsigned short*)dout)[o] = f2bf(acc[r]);
    }
  }
}

// ---------------------------------------------------------------------------
// host
// ---------------------------------------------------------------------------
extern "C" void kernel_launch(void* const* d_in, const int* in_sizes, int n_in,
                              void* d_out, int out_size, void* d_ws, size_t ws_size,
                              hipStream_t stream) {
  const void* x    = d_in[0];
  const void* traj = d_in[1];
  const void* w1l0 = d_in[2];
  const void* w1l1 = d_in[3];
  W2Ptrs w2;
  for (int l = 0; l < 7; l++) w2.p[l] = d_in[4 + l];

  char* ws = (char*)d_ws;
  double* exps          = (double*)(ws + 0);                 // 336*169*8
  float* dint           = (float*)(ws + 458752);             // 10*2048*4
  float* c8w            = (float*)(ws + 540672);             // 8*512*4
  unsigned short* c8bT  = (unsigned short*)(ws + 557056);    // 16*512*2
  unsigned short* dwt   = (unsigned short*)(ws + 573440);    // 512*2048*2
  float* feat           = (float*)(ws + 2670592);            // 512*160*4
  unsigned short* sig   = (unsigned short*)(ws + 2998272);   // 8192*2048*2
  unsigned short* f2    = (unsigned short*)(ws + 36552704);  // 8192*512*2
  unsigned short* et    = (unsigned short*)(ws + 44941312);  // 512*8192*2
  float* cp             = (float*)(ws + 53329920);           // 8*512*512*4
  int* flag             = (int*)(ws + 61718528);

  SetupArgs sa; QWArgs qa;
  for (int i = 0; i < 16; i++) sa.angA[i] = 2.0 * M_PI * (double)i / 16.0;
  static const double XB[8] = {
    -0.9602898564975363, -0.7966664774136267, -0.5255324099163290,
    -0.1834346424956498,  0.1834346424956498,  0.5255324099163290,
     0.7966664774136267,  0.9602898564975363};
  static const double WBv[8] = {
     0.1012285362903763, 0.2223810344533745, 0.3137066458778873,
     0.3626837833783620, 0.3626837833783620, 0.3137066458778873,
     0.2223810344533745, 0.1012285362903763};
  for (int i = 0; i < 8; i++) { sa.angB[i] = acos(XB[i]); qa.wb[i] = WBv[i]; }
  for (int i = 0; i < 8; i++) {
    double th = 2.0 * M_PI * (double)i / 8.0;
    double Mm[3][3] = {{cos(th), sin(th), 0.0},
                       {-sin(th), cos(th), 0.0},
                       {0.0, 0.0, 1.0}};
    double x0 = Mm[0][1], x1 = Mm[1][1], x2 = Mm[2][1];
    double bb = acos(fmax(-1.0, fmin(1.0, x1)));
    double aa = atan2(x0, x2);
    double ca_ = cos(aa), sa_ = sin(aa), cb_ = cos(bb), sb_ = sin(bb);
    double MY[3][3] = {{ca_, 0, sa_}, {0, 1, 0}, {-sa_, 0, ca_}};
    double MX[3][3] = {{1, 0, 0}, {0, cb_, -sb_}, {0, sb_, cb_}};
    double P1[3][3], Rr[3][3];
    for (int r = 0; r < 3; r++)
      for (int c = 0; c < 3; c++) {
        double s = 0.0;
        for (int k = 0; k < 3; k++) s += MY[r][k] * MX[k][c];
        P1[r][c] = s;
      }
    for (int r = 0; r < 3; r++)
      for (int c = 0; c < 3; c++) {
        double s = 0.0;
        for (int k = 0; k < 3; k++) s += P1[k][r] * Mm[k][c];  // P1^T @ M
        Rr[r][c] = s;
      }
    double gg = atan2(Rr[0][2], Rr[0][0]);
    sa.c8a[i] = aa; sa.c8b[i] = bb; sa.c8g[i] = gg;
  }

  k_exps<<<337, 64, 0, stream>>>(sa, exps, x, flag);
  k_assemble<<<2232, 64, 0, stream>>>(exps, qa, dwt, dint, c8w, c8bT,
                                      traj, w1l0, w1l1, feat, flag);
  k_sig<<<4096, 256, 0, stream>>>(feat, dint, sig);
  k_ebuild<<<16384, 256, 0, stream>>>(w2, c8w, et, flag);
  k_gemm2<<<512, 256, 0, stream>>>(sig, dwt, f2);
  k_gemm3<<<256, 256, 0, stream>>>(f2, et, cp);
  k_xc8red<<<5120, 64, 0, stream>>>(x, c8bT, cp, d_out, flag);
}

// Round 4
// 411.524 us; speedup vs baseline: 1.4128x; 1.4128x over previous
//
#include <hip/hip_runtime.h>
#include <hip/hip_bf16.h>
#include <math.h>

// ============================================================================
// EquiGroupSamplingC8 (f32 I/O confirmed by runtime sniff; bf16 path retained).
// R4: revert x_c8 to R2-proven 256-thr shuffle kernel (R3's 64-thr MFMA
// version was latency-bound: 234 us, 3.6% HBM, 11.9% occupancy). Split-K
// reduce merged into same dispatch. Rest unchanged from R3.
// ============================================================================

typedef __attribute__((ext_vector_type(8))) short bf16x8;
typedef __attribute__((ext_vector_type(4))) float f32x4;

__device__ const int c_offs[8] = {0, 1, 10, 35, 84, 165, 286, 455};

struct SetupArgs {
  double angA[16];              // 2*pi*k/16 (alpha and gamma grid)
  double angB[8];               // arccos(GL8 nodes)
  double c8a[8], c8b[8], c8g[8];
};
struct QWArgs { double wb[8]; };
struct W2Ptrs { const void* p[7]; };

__device__ __forceinline__ float bf2f(unsigned short u) {
  union { unsigned int i; float f; } v; v.i = ((unsigned int)u) << 16; return v.f;
}
__device__ __forceinline__ unsigned short f2bf(float f) {
  union { float f; unsigned int i; } v; v.f = f;
  unsigned int r = v.i + 0x7fffu + ((v.i >> 16) & 1u);
  return (unsigned short)(r >> 16);
}
__device__ __forceinline__ float in_val(const void* p, size_t i, int isf) {
  return isf ? ((const float*)p)[i] : bf2f(((const unsigned short*)p)[i]);
}
__device__ __forceinline__ void gl_lds16(const void* g, void* lds) {
  __builtin_amdgcn_global_load_lds(
      (const __attribute__((address_space(1))) unsigned int*)g,
      (__attribute__((address_space(3))) unsigned int*)lds, 16, 0, 0);
}

// ---------------------------------------------------------------------------
// K1: exp matrices. blocks [0,336) = 7 l * 48 items; block 336 = dtype sniff.
// ---------------------------------------------------------------------------
__global__ __launch_bounds__(64) void k_exps(SetupArgs args, double* exps,
                                             const void* x, int* flag) {
  __shared__ double Qr[169], Qi[169], G[169], Bm[169], R[169], T[169];
  __shared__ double snorm;
  __shared__ int cnt;
  int tid = threadIdx.x;

  if (blockIdx.x == 336) {           // dtype sniff: f32 N(0,1) magnitude band
    if (tid == 0) cnt = 0;
    __syncthreads();
    float v = ((const float*)x)[tid];
    float a = fabsf(v);
    int ok = (v == v) && (a > 9.0949470e-13f) && (a < 1.0995116e12f);
    atomicAdd(&cnt, ok);
    __syncthreads();
    if (tid == 0) *flag = (cnt >= 32) ? 1 : 0;
    return;
  }

  int l = blockIdx.x / 48, item = blockIdx.x % 48;
  int n = 2 * l + 1;

  for (int e = tid; e < n * n; e += 64) { Qr[e] = 0.0; Qi[e] = 0.0; }
  __syncthreads();
  if (tid == 0) {
    const double is2 = 0.70710678118654752440;
    for (int m = -l; m <= l; m++) {
      int r = l + m;
      if (m < 0) {
        Qr[r * n + (l - m)] = is2;
        Qi[r * n + (l + m)] = -is2;
      } else if (m == 0) {
        Qr[l * n + l] = 1.0;
      } else {
        double s = (m & 1) ? -1.0 : 1.0;
        Qr[r * n + (l + m)] = s * is2;
        Qi[r * n + (l - m)] = s * is2;
      }
    }
  }
  __syncthreads();
  { // multiply by (-1j)^l
    int lm = l & 3;
    double pr = (lm == 0) ? 1.0 : (lm == 2 ? -1.0 : 0.0);
    double pi = (lm == 1) ? -1.0 : (lm == 3 ? 1.0 : 0.0);
    for (int e = tid; e < n * n; e += 64) {
      double qr = Qr[e], qi = Qi[e];
      Qr[e] = qr * pr - qi * pi;
      Qi[e] = qr * pi + qi * pr;
    }
  }
  __syncthreads();

  double t; int axis;
  if (item < 16)      { t = args.angA[item];      axis = 1; }
  else if (item < 24) { t = args.angB[item - 16]; axis = 0; }
  else if (item < 32) { t = args.c8a[item - 24];  axis = 1; }
  else if (item < 40) { t = args.c8b[item - 32];  axis = 0; }
  else                { t = args.c8g[item - 40];  axis = 1; }

  double jj = (double)l;
  for (int e = tid; e < n * n; e += 64) {
    int r = e / n, c = e % n;
    double accr = 0.0;
    if (axis == 1) {
      for (int p = 0; p < n; p++) {
        double mp = (double)(p - l);
        double ar = Qr[p * n + r], ai = -Qi[p * n + r];
        double br = Qr[p * n + c], bi = Qi[p * n + c];
        accr += -mp * (ar * bi + ai * br);
      }
    } else {
      for (int p = 0; p < n; p++) {
        double xr = 0.0, xi = 0.0;
        if (p > 0) {
          double m = (double)(p - 1 - l);
          double v = -0.5 * sqrt(jj * (jj + 1.0) - m * (m + 1.0));
          xr += v * Qr[(p - 1) * n + c]; xi += v * Qi[(p - 1) * n + c];
        }
        if (p < n - 1) {
          double m = (double)(p + 1 - l);
          double v = 0.5 * sqrt(jj * (jj + 1.0) - m * (m - 1.0));
          xr += v * Qr[(p + 1) * n + c]; xi += v * Qi[(p + 1) * n + c];
        }
        double ar = Qr[p * n + r], ai = -Qi[p * n + r];
        accr += ar * xr - ai * xi;
      }
    }
    G[e] = accr;
  }
  __syncthreads();
  for (int e = tid; e < n * n; e += 64) Bm[e] = t * G[e];
  __syncthreads();
  if (tid == 0) {
    double mx = 0.0;
    for (int r = 0; r < n; r++) {
      double s = 0.0;
      for (int c = 0; c < n; c++) s += fabs(Bm[r * n + c]);
      if (s > mx) mx = s;
    }
    int s = 0;
    while (mx > 0.5 && s < 48) { mx *= 0.5; s++; }
    snorm = (double)s;
  }
  __syncthreads();
  int sq = (int)snorm;
  double sc = 1.0;
  for (int i = 0; i < sq; i++) sc *= 0.5;
  for (int e = tid; e < n * n; e += 64) Bm[e] *= sc;
  __syncthreads();
  for (int e = tid; e < n * n; e += 64) {
    int r = e / n, c = e % n;
    R[e] = Bm[e] / 16.0 + ((r == c) ? 1.0 : 0.0);
  }
  __syncthreads();
  for (int k = 15; k >= 1; k--) {
    for (int e = tid; e < n * n; e += 64) {
      int r = e / n, c = e % n;
      double acc = 0.0;
      for (int p = 0; p < n; p++) acc += Bm[r * n + p] * R[p * n + c];
      T[e] = acc / (double)k + ((r == c) ? 1.0 : 0.0);
    }
    __syncthreads();
    for (int e = tid; e < n * n; e += 64) R[e] = T[e];
    __syncthreads();
  }
  for (int i = 0; i < sq; i++) {
    for (int e = tid; e < n * n; e += 64) {
      int r = e / n, c = e % n;
      double acc = 0.0;
      for (int p = 0; p < n; p++) acc += R[r * n + p] * R[p * n + c];
      T[e] = acc;
    }
    __syncthreads();
    for (int e = tid; e < n * n; e += 64) R[e] = T[e];
    __syncthreads();
  }
  double* out = exps + (size_t)blockIdx.x * 169;
  for (int e = tid; e < n * n; e += 64) out[e] = R[e];
}

// ---------------------------------------------------------------------------
// K2: assemble. blocks [0,896) = (l,a,b), loop over 16 c: dwt/dint;
// [896,952) = (l,ci) c8 -> c8w f32; [952,2232) = feat (proj_1).
// ---------------------------------------------------------------------------
__global__ __launch_bounds__(64) void k_assemble(const double* exps, QWArgs qw,
                                                 unsigned short* dwt, float* dint,
                                                 float* c8w,
                                                 const void* traj, const void* w1l0,
                                                 const void* w1l1, float* feat,
                                                 const int* flag) {
  __shared__ double Ea[169], Eb[169], Ec[169], T1[169];
  int tid = threadIdx.x;
  int bx = blockIdx.x;

  if (bx >= 952) {                    // ---- feat (proj_1) ----
    int isf = __builtin_amdgcn_readfirstlane(flag[0]);
    int idx = (bx - 952) * 64 + tid;
    if (idx >= 512 * 160) return;
    int bt = idx / 160, rem = idx % 160;
    int c = rem / 10, i = rem % 10;
    float v;
    if (i == 0) {
      v = in_val(traj, bt * 10 + 9, isf) * in_val(w1l0, c, isf);
    } else {
      int ii = i - 1, w = ii / 3, m = ii % 3;
      float acc = 0.0f;
      for (int u = 0; u < 3; u++)
        acc += in_val(traj, bt * 10 + 3 * u + m, isf) *
               in_val(w1l1, c * 9 + u * 3 + w, isf);
      v = acc * 0.57735026918962576f;
    }
    feat[idx] = v;
    return;
  }

  if (bx >= 896) {                    // ---- C8 points ----
    int idx = bx - 896;
    int l = idx / 8, ci = idx % 8;
    int d = 2 * l + 1;
    const double* pa = exps + (size_t)(l * 48 + 24 + ci) * 169;
    const double* pb = exps + (size_t)(l * 48 + 32 + ci) * 169;
    const double* pc = exps + (size_t)(l * 48 + 40 + ci) * 169;
    for (int e = tid; e < d * d; e += 64) { Ea[e] = pa[e]; Eb[e] = pb[e]; Ec[e] = pc[e]; }
    __syncthreads();
    for (int e = tid; e < d * d; e += 64) {
      int r = e / d, c = e % d; double acc = 0.0;
      for (int p = 0; p < d; p++) acc += Ea[r * d + p] * Eb[p * d + c];
      T1[e] = acc;
    }
    __syncthreads();
    double scale = sqrt((double)(2 * l + 1));
    for (int e = tid; e < d * d; e += 64) {
      int r = e / d, c = e % d; double acc = 0.0;
      for (int p = 0; p < d; p++) acc += T1[r * d + p] * Ec[p * d + c];
      c8w[ci * 512 + c_offs[l] + e] = (float)(scale * acc);
    }
    if (l == 0) {
      for (int jz = 455 + tid; jz < 512; jz += 64)
        c8w[ci * 512 + jz] = 0.0f;
    }
    return;
  }

  // ---- grid (l, a, b), loop c ----
  int l = bx / 128, ab = bx % 128;
  int a = ab >> 3, b = ab & 7;
  int d = 2 * l + 1;
  const double* pa = exps + (size_t)(l * 48 + a) * 169;
  const double* pb = exps + (size_t)(l * 48 + 16 + b) * 169;
  for (int e = tid; e < d * d; e += 64) { Ea[e] = pa[e]; Eb[e] = pb[e]; }
  __syncthreads();
  for (int e = tid; e < d * d; e += 64) {
    int r = e / d, c = e % d; double acc = 0.0;
    for (int p = 0; p < d; p++) acc += Ea[r * d + p] * Eb[p * d + c];
    T1[e] = acc;
  }
  double scale = sqrt((double)(2 * l + 1));
  double qwv = qw.wb[b] * (1.0 / 512.0);
  const double* ctab = exps + (size_t)(l * 48) * 169;   // items [0,16) = gamma
  for (int cc = 0; cc < 16; cc++) {
    __syncthreads();
    const double* pc = ctab + (size_t)cc * 169;
    for (int e = tid; e < d * d; e += 64) Ec[e] = pc[e];
    __syncthreads();
    int g = a * 128 + b * 16 + cc;
    for (int e = tid; e < d * d; e += 64) {
      int r = e / d, c = e % d; double acc = 0.0;
      for (int p = 0; p < d; p++) acc += T1[r * d + p] * Ec[p * d + c];
      int j = c_offs[l] + e;
      dwt[(size_t)j * 2048 + g] = f2bf((float)(scale * acc * qwv));
      if (l == 1) dint[(size_t)(1 + e) * 2048 + g] = (float)(scale * acc);
      if (l == 0 && e == 0) dint[g] = (float)(scale * acc);
    }
    if (l == 0) {
      for (int jz = 455 + tid; jz < 512; jz += 64)
        dwt[(size_t)jz * 2048 + g] = 0;
    }
  }
}

// ---------------------------------------------------------------------------
// K3: sig [8192][2048] bf16 = relu(feat @ D_IN^T) * sqrt(2)
// ---------------------------------------------------------------------------
__global__ __launch_bounds__(256) void k_sig(const float* feat, const float* dint,
                                             unsigned short* sig) {
  int bi = blockIdx.x >> 3;
  int g = ((blockIdx.x & 7) << 8) + threadIdx.x;
  float din[10];
#pragma unroll
  for (int i = 0; i < 10; i++) din[i] = dint[(size_t)i * 2048 + g];
  const float* fr = feat + bi * 160;
  for (int cc = 0; cc < 16; cc++) {
    float acc = 0.0f;
#pragma unroll
    for (int i = 0; i < 10; i++) acc += fr[cc * 10 + i] * din[i];
    acc = fmaxf(acc, 0.0f) * 1.41421356237309505f;
    sig[(size_t)(bi * 16 + cc) * 2048 + g] = f2bf(acc);
  }
}

// ---------------------------------------------------------------------------
// K4: E_T [512][8192] bf16: row n=g*8+i, col k=f*512+jj
// ---------------------------------------------------------------------------
__global__ __launch_bounds__(256) void k_ebuild(W2Ptrs w2, const float* c8w,
                                                unsigned short* et, const int* flag) {
  int isf = __builtin_amdgcn_readfirstlane(flag[0]);
  int idx = blockIdx.x * 256 + threadIdx.x;     // 512*16*512
  int n = idx >> 13;
  int rest = idx & 8191;
  int f = rest >> 9, jj = rest & 511;
  size_t oaddr = (size_t)n * 8192 + f * 512 + jj;
  if (jj >= 455) { et[oaddr] = 0; return; }
  int l = 0;
  while (jj >= c_offs[l + 1]) l++;
  int d = 2 * l + 1;
  int rloc = jj - c_offs[l];
  int u = rloc / d, m = rloc % d;
  int g = n >> 3, i = n & 7;
  const void* wp = w2.p[l];
  float acc = 0.0f;
  for (int w = 0; w < d; w++) {
    float wv = in_val(wp, ((size_t)(f * 64 + g) * d + u) * d + w, isf);
    acc += wv * c8w[i * 512 + c_offs[l] + w * d + m];
  }
  acc *= rsqrtf((float)(16 * d));
  et[oaddr] = f2bf(acc);
}

// ---------------------------------------------------------------------------
// K5: GEMM2: f2[8192][512] = sig[8192][2048] @ dwt^T. BM=64 BN=128 BK=32.
// ---------------------------------------------------------------------------
__global__ __launch_bounds__(256) void k_gemm2(const unsigned short* A,
                                               const unsigned short* B,
                                               unsigned short* C) {
  __shared__ __align__(16) unsigned short As[64 * 32];
  __shared__ __align__(16) unsigned short Bs[128 * 32];
  int tid = threadIdx.x;
  int lane = tid & 63, wid = tid >> 6;
  int mt = blockIdx.x >> 2, nt = blockIdx.x & 3;
  int m0 = mt * 64, n0 = nt * 128;
  int wm = wid >> 1, wn = wid & 1;
  f32x4 acc[2][4];
#pragma unroll
  for (int a = 0; a < 2; a++)
#pragma unroll
    for (int b = 0; b < 4; b++) acc[a][b] = (f32x4){0.f, 0.f, 0.f, 0.f};
  int c0 = tid;
  int ar = c0 >> 2, ak = (c0 & 3) * 8;
  const unsigned short* Abase = A + (size_t)m0 * 2048;
  const unsigned short* Bbase = B + (size_t)n0 * 2048;
  int row = lane & 15, kq = (lane >> 4) * 8;
  for (int kt = 0; kt < 64; kt++) {
    int k0 = kt * 32;
    gl_lds16(Abase + (size_t)ar * 2048 + k0 + ak, &As[wid * 512]);
    gl_lds16(Bbase + (size_t)ar * 2048 + k0 + ak, &Bs[wid * 512]);
    gl_lds16(Bbase + (size_t)(ar + 64) * 2048 + k0 + ak, &Bs[2048 + wid * 512]);
    __syncthreads();
    bf16x8 af[2], bfr[4];
#pragma unroll
    for (int im = 0; im < 2; im++)
      af[im] = *(const bf16x8*)&As[(wm * 32 + im * 16 + row) * 32 + kq];
#pragma unroll
    for (int in = 0; in < 4; in++)
      bfr[in] = *(const bf16x8*)&Bs[(wn * 64 + in * 16 + row) * 32 + kq];
#pragma unroll
    for (int im = 0; im < 2; im++)
#pragma unroll
      for (int in = 0; in < 4; in++)
        acc[im][in] = __builtin_amdgcn_mfma_f32_16x16x32_bf16(af[im], bfr[in],
                                                              acc[im][in], 0, 0, 0);
    __syncthreads();
  }
  int col = lane & 15, rq = (lane >> 4) * 4;
#pragma unroll
  for (int im = 0; im < 2; im++)
#pragma unroll
    for (int in = 0; in < 4; in++)
#pragma unroll
      for (int r = 0; r < 4; r++) {
        int rr = m0 + wm * 32 + im * 16 + rq + r;
        int cc = n0 + wn * 64 + in * 16 + col;
        C[(size_t)rr * 512 + cc] = f2bf(acc[im][in][r]);
      }
}

// ---------------------------------------------------------------------------
// K6: GEMM3 split-K=8: Cp[kc][512][512] f32 = f2[512][8192] @ E (E_T staged)
// ---------------------------------------------------------------------------
__global__ __launch_bounds__(256) void k_gemm3(const unsigned short* A,
                                               const unsigned short* B, float* Cp) {
  __shared__ __align__(16) unsigned short As[64 * 32];
  __shared__ __align__(16) unsigned short Bs[128 * 32];
  int tid = threadIdx.x, lane = tid & 63, wid = tid >> 6;
  int kc = blockIdx.x >> 5;
  int mt = (blockIdx.x >> 2) & 7, nt = blockIdx.x & 3;
  int m0 = mt * 64, n0 = nt * 128;
  int wm = wid >> 1, wn = wid & 1;
  f32x4 acc[2][4];
#pragma unroll
  for (int a = 0; a < 2; a++)
#pragma unroll
    for (int b = 0; b < 4; b++) acc[a][b] = (f32x4){0.f, 0.f, 0.f, 0.f};
  int c0 = tid;
  int ar = c0 >> 2, ak = (c0 & 3) * 8;
  const unsigned short* Abase = A + (size_t)m0 * 8192 + kc * 1024;
  const unsigned short* Bbase = B + (size_t)n0 * 8192 + kc * 1024;
  int row = lane & 15, kq = (lane >> 4) * 8;
  for (int kt = 0; kt < 32; kt++) {
    int k0 = kt * 32;
    gl_lds16(Abase + (size_t)ar * 8192 + k0 + ak, &As[wid * 512]);
    gl_lds16(Bbase + (size_t)ar * 8192 + k0 + ak, &Bs[wid * 512]);
    gl_lds16(Bbase + (size_t)(ar + 64) * 8192 + k0 + ak, &Bs[2048 + wid * 512]);
    __syncthreads();
    bf16x8 af[2], bfr[4];
#pragma unroll
    for (int im = 0; im < 2; im++)
      af[im] = *(const bf16x8*)&As[(wm * 32 + im * 16 + row) * 32 + kq];
#pragma unroll
    for (int in = 0; in < 4; in++)
      bfr[in] = *(const bf16x8*)&Bs[(wn * 64 + in * 16 + row) * 32 + kq];
#pragma unroll
    for (int im = 0; im < 2; im++)
#pragma unroll
      for (int in = 0; in < 4; in++)
        acc[im][in] = __builtin_amdgcn_mfma_f32_16x16x32_bf16(af[im], bfr[in],
                                                              acc[im][in], 0, 0, 0);
    __syncthreads();
  }
  int col = lane & 15, rq = (lane >> 4) * 4;
  float* out = Cp + (size_t)kc * 262144;
#pragma unroll
  for (int im = 0; im < 2; im++)
#pragma unroll
    for (int in = 0; in < 4; in++)
#pragma unroll
      for (int r = 0; r < 4; r++) {
        int rr = m0 + wm * 32 + im * 16 + rq + r;
        int cc = n0 + wn * 64 + in * 16 + col;
        out[(size_t)rr * 512 + cc] = acc[im][in][r];
      }
}

// ---------------------------------------------------------------------------
// K7: blocks [0,512): x_c8 = x @ C8W^T (R2-proven: wave/row, shuffle reduce).
//     blocks [512,768): split-K reduce -> traj_c8.
// ---------------------------------------------------------------------------
__global__ __launch_bounds__(256) void k_xc8r(const void* x, const float* c8w,
                                              const float* Cp, void* dout,
                                              const int* flag) {
  int tid = threadIdx.x, lane = tid & 63, wid = tid >> 6;
  int isf = __builtin_amdgcn_readfirstlane(flag[0]);

  if (blockIdx.x >= 512) {            // ---- split-K reduce ----
    int idx = (blockIdx.x - 512) * 256 + tid;    // [0, 65536)
    const float4* c = (const float4*)Cp;
    float s0 = 0.f, s1 = 0.f, s2 = 0.f, s3 = 0.f;
#pragma unroll
    for (int p = 0; p < 8; p++) {
      float4 v = c[idx + p * 65536];
      s0 += v.x; s1 += v.y; s2 += v.z; s3 += v.w;
    }
    size_t base = 524288 + (size_t)idx * 4;
    if (isf) {
      float4 o; o.x = s0; o.y = s1; o.z = s2; o.w = s3;
      *(float4*)((float*)dout + base) = o;
    } else {
      unsigned int p0 = (unsigned int)f2bf(s0) | ((unsigned int)f2bf(s1) << 16);
      unsigned int p1 = (unsigned int)f2bf(s2) | ((unsigned int)f2bf(s3) << 16);
      uint2 pk; pk.x = p0; pk.y = p1;
      *(uint2*)((unsigned short*)dout + base) = pk;
    }
    return;
  }

  // ---- x_c8: wave per row, lane j covers col j band, shuffle reduce ----
  int gw = blockIdx.x * 4 + wid;      // 2048 waves, 32 rows each
  float cw[8][8];
#pragma unroll
  for (int t = 0; t < 8; t++)
#pragma unroll
    for (int i = 0; i < 8; i++)
      cw[t][i] = c8w[i * 512 + t * 64 + lane];
  const float* xf = (const float*)x;
  const unsigned short* xh = (const unsigned short*)x;
  for (int r = gw * 32; r < gw * 32 + 32; r++) {
    float acc[8];
#pragma unroll
    for (int i = 0; i < 8; i++) acc[i] = 0.0f;
    if (isf) {
      const float* xr = xf + (size_t)r * 455;
#pragma unroll
      for (int t = 0; t < 8; t++) {
        int j = t * 64 + lane;
        float xv = (j < 455) ? xr[j] : 0.0f;
#pragma unroll
        for (int i = 0; i < 8; i++) acc[i] += xv * cw[t][i];
      }
    } else {
      const unsigned short* xr = xh + (size_t)r * 455;
#pragma unroll
      for (int t = 0; t < 8; t++) {
        int j = t * 64 + lane;
        float xv = (j < 455) ? bf2f(xr[j]) : 0.0f;
#pragma unroll
        for (int i = 0; i < 8; i++) acc[i] += xv * cw[t][i];
      }
    }
#pragma unroll
    for (int off = 32; off >= 1; off >>= 1)
#pragma unroll
      for (int i = 0; i < 8; i++) acc[i] += __shfl_xor(acc[i], off);
    float v = acc[0];
    v = (lane == 1) ? acc[1] : v;
    v = (lane == 2) ? acc[2] : v;
    v = (lane == 3) ? acc[3] : v;
    v = (lane == 4) ? acc[4] : v;
    v = (lane == 5) ? acc[5] : v;
    v = (lane == 6) ? acc[6] : v;
    v = (lane == 7) ? acc[7] : v;
    if (lane < 8) {
      if (isf) ((float*)dout)[(size_t)r * 8 + lane] = v;
      else     ((unsigned short*)dout)[(size_t)r * 8 + lane] = f2bf(v);
    }
  }
}

// ---------------------------------------------------------------------------
// host
// ---------------------------------------------------------------------------
extern "C" void kernel_launch(void* const* d_in, const int* in_sizes, int n_in,
                              void* d_out, int out_size, void* d_ws, size_t ws_size,
                              hipStream_t stream) {
  const void* x    = d_in[0];
  const void* traj = d_in[1];
  const void* w1l0 = d_in[2];
  const void* w1l1 = d_in[3];
  W2Ptrs w2;
  for (int l = 0; l < 7; l++) w2.p[l] = d_in[4 + l];

  char* ws = (char*)d_ws;
  double* exps          = (double*)(ws + 0);                 // 336*169*8
  float* dint           = (float*)(ws + 458752);             // 10*2048*4
  float* c8w            = (float*)(ws + 540672);             // 8*512*4
  unsigned short* dwt   = (unsigned short*)(ws + 573440);    // 512*2048*2
  float* feat           = (float*)(ws + 2670592);            // 512*160*4
  unsigned short* sig   = (unsigned short*)(ws + 2998272);   // 8192*2048*2
  unsigned short* f2    = (unsigned short*)(ws + 36552704);  // 8192*512*2
  unsigned short* et    = (unsigned short*)(ws + 44941312);  // 512*8192*2
  float* cp             = (float*)(ws + 53329920);           // 8*512*512*4
  int* flag             = (int*)(ws + 61718528);

  SetupArgs sa; QWArgs qa;
  for (int i = 0; i < 16; i++) sa.angA[i] = 2.0 * M_PI * (double)i / 16.0;
  static const double XB[8] = {
    -0.9602898564975363, -0.7966664774136267, -0.5255324099163290,
    -0.1834346424956498,  0.1834346424956498,  0.5255324099163290,
     0.7966664774136267,  0.9602898564975363};
  static const double WBv[8] = {
     0.1012285362903763, 0.2223810344533745, 0.3137066458778873,
     0.3626837833783620, 0.3626837833783620, 0.3137066458778873,
     0.2223810344533745, 0.1012285362903763};
  for (int i = 0; i < 8; i++) { sa.angB[i] = acos(XB[i]); qa.wb[i] = WBv[i]; }
  for (int i = 0; i < 8; i++) {
    double th = 2.0 * M_PI * (double)i / 8.0;
    double Mm[3][3] = {{cos(th), sin(th), 0.0},
                       {-sin(th), cos(th), 0.0},
                       {0.0, 0.0, 1.0}};
    double x0 = Mm[0][1], x1 = Mm[1][1], x2 = Mm[2][1];
    double bb = acos(fmax(-1.0, fmin(1.0, x1)));
    double aa = atan2(x0, x2);
    double ca_ = cos(aa), sa_ = sin(aa), cb_ = cos(bb), sb_ = sin(bb);
    double MY[3][3] = {{ca_, 0, sa_}, {0, 1, 0}, {-sa_, 0, ca_}};
    double MX[3][3] = {{1, 0, 0}, {0, cb_, -sb_}, {0, sb_, cb_}};
    double P1[3][3], Rr[3][3];
    for (int r = 0; r < 3; r++)
      for (int c = 0; c < 3; c++) {
        double s = 0.0;
        for (int k = 0; k < 3; k++) s += MY[r][k] * MX[k][c];
        P1[r][c] = s;
      }
    for (int r = 0; r < 3; r++)
      for (int c = 0; c < 3; c++) {
        double s = 0.0;
        for (int k = 0; k < 3; k++) s += P1[k][r] * Mm[k][c];  // P1^T @ M
        Rr[r][c] = s;
      }
    double gg = atan2(Rr[0][2], Rr[0][0]);
    sa.c8a[i] = aa; sa.c8b[i] = bb; sa.c8g[i] = gg;
  }

  k_exps<<<337, 64, 0, stream>>>(sa, exps, x, flag);
  k_assemble<<<2232, 64, 0, stream>>>(exps, qa, dwt, dint, c8w,
                                      traj, w1l0, w1l1, feat, flag);
  k_sig<<<4096, 256, 0, stream>>>(feat, dint, sig);
  k_ebuild<<<16384, 256, 0, stream>>>(w2, c8w, et, flag);
  k_gemm2<<<512, 256, 0, stream>>>(sig, dwt, f2);
  k_gemm3<<<256, 256, 0, stream>>>(f2, et, cp);
  k_xc8r<<<768, 256, 0, stream>>>(x, c8w, cp, d_out, flag);
}

// Round 5
// 381.414 us; speedup vs baseline: 1.5243x; 1.0789x over previous
//
#include <hip/hip_runtime.h>
#include <hip/hip_bf16.h>
#include <math.h>

// ============================================================================
// EquiGroupSamplingC8 (f32 I/O confirmed by runtime sniff; bf16 path retained).
// R5: GEMM2 retiled to 32x32x16 MFMA BM128/BN64/BK64 with XOR-swizzled LDS;
// xc8r wave count doubled (16 rows/wave); assemble gamma-loop split 4-way.
// ============================================================================

typedef __attribute__((ext_vector_type(8))) short bf16x8;
typedef __attribute__((ext_vector_type(4))) float f32x4;
typedef __attribute__((ext_vector_type(16))) float f32x16;

__device__ const int c_offs[8] = {0, 1, 10, 35, 84, 165, 286, 455};

struct SetupArgs {
  double angA[16];              // 2*pi*k/16 (alpha and gamma grid)
  double angB[8];               // arccos(GL8 nodes)
  double c8a[8], c8b[8], c8g[8];
};
struct QWArgs { double wb[8]; };
struct W2Ptrs { const void* p[7]; };

__device__ __forceinline__ float bf2f(unsigned short u) {
  union { unsigned int i; float f; } v; v.i = ((unsigned int)u) << 16; return v.f;
}
__device__ __forceinline__ unsigned short f2bf(float f) {
  union { float f; unsigned int i; } v; v.f = f;
  unsigned int r = v.i + 0x7fffu + ((v.i >> 16) & 1u);
  return (unsigned short)(r >> 16);
}
__device__ __forceinline__ float in_val(const void* p, size_t i, int isf) {
  return isf ? ((const float*)p)[i] : bf2f(((const unsigned short*)p)[i]);
}
__device__ __forceinline__ void gl_lds16(const void* g, void* lds) {
  __builtin_amdgcn_global_load_lds(
      (const __attribute__((address_space(1))) unsigned int*)g,
      (__attribute__((address_space(3))) unsigned int*)lds, 16, 0, 0);
}

// ---------------------------------------------------------------------------
// K1: exp matrices. blocks [0,336) = 7 l * 48 items; block 336 = dtype sniff.
// ---------------------------------------------------------------------------
__global__ __launch_bounds__(64) void k_exps(SetupArgs args, double* exps,
                                             const void* x, int* flag) {
  __shared__ double Qr[169], Qi[169], G[169], Bm[169], R[169], T[169];
  __shared__ double snorm;
  __shared__ int cnt;
  int tid = threadIdx.x;

  if (blockIdx.x == 336) {           // dtype sniff: f32 N(0,1) magnitude band
    if (tid == 0) cnt = 0;
    __syncthreads();
    float v = ((const float*)x)[tid];
    float a = fabsf(v);
    int ok = (v == v) && (a > 9.0949470e-13f) && (a < 1.0995116e12f);
    atomicAdd(&cnt, ok);
    __syncthreads();
    if (tid == 0) *flag = (cnt >= 32) ? 1 : 0;
    return;
  }

  int l = blockIdx.x / 48, item = blockIdx.x % 48;
  int n = 2 * l + 1;

  for (int e = tid; e < n * n; e += 64) { Qr[e] = 0.0; Qi[e] = 0.0; }
  __syncthreads();
  if (tid == 0) {
    const double is2 = 0.70710678118654752440;
    for (int m = -l; m <= l; m++) {
      int r = l + m;
      if (m < 0) {
        Qr[r * n + (l - m)] = is2;
        Qi[r * n + (l + m)] = -is2;
      } else if (m == 0) {
        Qr[l * n + l] = 1.0;
      } else {
        double s = (m & 1) ? -1.0 : 1.0;
        Qr[r * n + (l + m)] = s * is2;
        Qi[r * n + (l - m)] = s * is2;
      }
    }
  }
  __syncthreads();
  { // multiply by (-1j)^l
    int lm = l & 3;
    double pr = (lm == 0) ? 1.0 : (lm == 2 ? -1.0 : 0.0);
    double pi = (lm == 1) ? -1.0 : (lm == 3 ? 1.0 : 0.0);
    for (int e = tid; e < n * n; e += 64) {
      double qr = Qr[e], qi = Qi[e];
      Qr[e] = qr * pr - qi * pi;
      Qi[e] = qr * pi + qi * pr;
    }
  }
  __syncthreads();

  double t; int axis;
  if (item < 16)      { t = args.angA[item];      axis = 1; }
  else if (item < 24) { t = args.angB[item - 16]; axis = 0; }
  else if (item < 32) { t = args.c8a[item - 24];  axis = 1; }
  else if (item < 40) { t = args.c8b[item - 32];  axis = 0; }
  else                { t = args.c8g[item - 40];  axis = 1; }

  double jj = (double)l;
  for (int e = tid; e < n * n; e += 64) {
    int r = e / n, c = e % n;
    double accr = 0.0;
    if (axis == 1) {
      for (int p = 0; p < n; p++) {
        double mp = (double)(p - l);
        double ar = Qr[p * n + r], ai = -Qi[p * n + r];
        double br = Qr[p * n + c], bi = Qi[p * n + c];
        accr += -mp * (ar * bi + ai * br);
      }
    } else {
      for (int p = 0; p < n; p++) {
        double xr = 0.0, xi = 0.0;
        if (p > 0) {
          double m = (double)(p - 1 - l);
          double v = -0.5 * sqrt(jj * (jj + 1.0) - m * (m + 1.0));
          xr += v * Qr[(p - 1) * n + c]; xi += v * Qi[(p - 1) * n + c];
        }
        if (p < n - 1) {
          double m = (double)(p + 1 - l);
          double v = 0.5 * sqrt(jj * (jj + 1.0) - m * (m - 1.0));
          xr += v * Qr[(p + 1) * n + c]; xi += v * Qi[(p + 1) * n + c];
        }
        double ar = Qr[p * n + r], ai = -Qi[p * n + r];
        accr += ar * xr - ai * xi;
      }
    }
    G[e] = accr;
  }
  __syncthreads();
  for (int e = tid; e < n * n; e += 64) Bm[e] = t * G[e];
  __syncthreads();
  if (tid == 0) {
    double mx = 0.0;
    for (int r = 0; r < n; r++) {
      double s = 0.0;
      for (int c = 0; c < n; c++) s += fabs(Bm[r * n + c]);
      if (s > mx) mx = s;
    }
    int s = 0;
    while (mx > 0.5 && s < 48) { mx *= 0.5; s++; }
    snorm = (double)s;
  }
  __syncthreads();
  int sq = (int)snorm;
  double sc = 1.0;
  for (int i = 0; i < sq; i++) sc *= 0.5;
  for (int e = tid; e < n * n; e += 64) Bm[e] *= sc;
  __syncthreads();
  for (int e = tid; e < n * n; e += 64) {
    int r = e / n, c = e % n;
    R[e] = Bm[e] / 16.0 + ((r == c) ? 1.0 : 0.0);
  }
  __syncthreads();
  for (int k = 15; k >= 1; k--) {
    for (int e = tid; e < n * n; e += 64) {
      int r = e / n, c = e % n;
      double acc = 0.0;
      for (int p = 0; p < n; p++) acc += Bm[r * n + p] * R[p * n + c];
      T[e] = acc / (double)k + ((r == c) ? 1.0 : 0.0);
    }
    __syncthreads();
    for (int e = tid; e < n * n; e += 64) R[e] = T[e];
    __syncthreads();
  }
  for (int i = 0; i < sq; i++) {
    for (int e = tid; e < n * n; e += 64) {
      int r = e / n, c = e % n;
      double acc = 0.0;
      for (int p = 0; p < n; p++) acc += R[r * n + p] * R[p * n + c];
      T[e] = acc;
    }
    __syncthreads();
    for (int e = tid; e < n * n; e += 64) R[e] = T[e];
    __syncthreads();
  }
  double* out = exps + (size_t)blockIdx.x * 169;
  for (int e = tid; e < n * n; e += 64) out[e] = R[e];
}

// ---------------------------------------------------------------------------
// K2: assemble. blocks [0,3584) = (l,a,b,cgrp) each 4 gammas: dwt/dint;
// [3584,3640) = (l,ci) c8 -> c8w f32; [3640,4920) = feat (proj_1).
// ---------------------------------------------------------------------------
__global__ __launch_bounds__(64) void k_assemble(const double* exps, QWArgs qw,
                                                 unsigned short* dwt, float* dint,
                                                 float* c8w,
                                                 const void* traj, const void* w1l0,
                                                 const void* w1l1, float* feat,
                                                 const int* flag) {
  __shared__ double Ea[169], Eb[169], Ec[169], T1[169];
  int tid = threadIdx.x;
  int bx = blockIdx.x;

  if (bx >= 3640) {                   // ---- feat (proj_1) ----
    int isf = __builtin_amdgcn_readfirstlane(flag[0]);
    int idx = (bx - 3640) * 64 + tid;
    if (idx >= 512 * 160) return;
    int bt = idx / 160, rem = idx % 160;
    int c = rem / 10, i = rem % 10;
    float v;
    if (i == 0) {
      v = in_val(traj, bt * 10 + 9, isf) * in_val(w1l0, c, isf);
    } else {
      int ii = i - 1, w = ii / 3, m = ii % 3;
      float acc = 0.0f;
      for (int u = 0; u < 3; u++)
        acc += in_val(traj, bt * 10 + 3 * u + m, isf) *
               in_val(w1l1, c * 9 + u * 3 + w, isf);
      v = acc * 0.57735026918962576f;
    }
    feat[idx] = v;
    return;
  }

  if (bx >= 3584) {                   // ---- C8 points ----
    int idx = bx - 3584;
    int l = idx / 8, ci = idx % 8;
    int d = 2 * l + 1;
    const double* pa = exps + (size_t)(l * 48 + 24 + ci) * 169;
    const double* pb = exps + (size_t)(l * 48 + 32 + ci) * 169;
    const double* pc = exps + (size_t)(l * 48 + 40 + ci) * 169;
    for (int e = tid; e < d * d; e += 64) { Ea[e] = pa[e]; Eb[e] = pb[e]; Ec[e] = pc[e]; }
    __syncthreads();
    for (int e = tid; e < d * d; e += 64) {
      int r = e / d, c = e % d; double acc = 0.0;
      for (int p = 0; p < d; p++) acc += Ea[r * d + p] * Eb[p * d + c];
      T1[e] = acc;
    }
    __syncthreads();
    double scale = sqrt((double)(2 * l + 1));
    for (int e = tid; e < d * d; e += 64) {
      int r = e / d, c = e % d; double acc = 0.0;
      for (int p = 0; p < d; p++) acc += T1[r * d + p] * Ec[p * d + c];
      c8w[ci * 512 + c_offs[l] + e] = (float)(scale * acc);
    }
    if (l == 0) {
      for (int jz = 455 + tid; jz < 512; jz += 64)
        c8w[ci * 512 + jz] = 0.0f;
    }
    return;
  }

  // ---- grid (l, a, b, cgrp), loop 4 gammas ----
  int l = bx / 512, rem = bx % 512;
  int a = rem >> 5, b = (rem >> 2) & 7, cg = rem & 3;
  int d = 2 * l + 1;
  const double* pa = exps + (size_t)(l * 48 + a) * 169;
  const double* pb = exps + (size_t)(l * 48 + 16 + b) * 169;
  for (int e = tid; e < d * d; e += 64) { Ea[e] = pa[e]; Eb[e] = pb[e]; }
  __syncthreads();
  for (int e = tid; e < d * d; e += 64) {
    int r = e / d, c = e % d; double acc = 0.0;
    for (int p = 0; p < d; p++) acc += Ea[r * d + p] * Eb[p * d + c];
    T1[e] = acc;
  }
  double scale = sqrt((double)(2 * l + 1));
  double qwv = qw.wb[b] * (1.0 / 512.0);
  const double* ctab = exps + (size_t)(l * 48) * 169;   // items [0,16) = gamma
  for (int cc = cg * 4; cc < cg * 4 + 4; cc++) {
    __syncthreads();
    const double* pc = ctab + (size_t)cc * 169;
    for (int e = tid; e < d * d; e += 64) Ec[e] = pc[e];
    __syncthreads();
    int g = a * 128 + b * 16 + cc;
    for (int e = tid; e < d * d; e += 64) {
      int r = e / d, c = e % d; double acc = 0.0;
      for (int p = 0; p < d; p++) acc += T1[r * d + p] * Ec[p * d + c];
      int j = c_offs[l] + e;
      dwt[(size_t)j * 2048 + g] = f2bf((float)(scale * acc * qwv));
      if (l == 1) dint[(size_t)(1 + e) * 2048 + g] = (float)(scale * acc);
      if (l == 0 && e == 0) dint[g] = (float)(scale * acc);
    }
    if (l == 0) {
      for (int jz = 455 + tid; jz < 512; jz += 64)
        dwt[(size_t)jz * 2048 + g] = 0;
    }
  }
}

// ---------------------------------------------------------------------------
// K3: sig [8192][2048] bf16 = relu(feat @ D_IN^T) * sqrt(2)
// ---------------------------------------------------------------------------
__global__ __launch_bounds__(256) void k_sig(const float* feat, const float* dint,
                                             unsigned short* sig) {
  int bi = blockIdx.x >> 3;
  int g = ((blockIdx.x & 7) << 8) + threadIdx.x;
  float din[10];
#pragma unroll
  for (int i = 0; i < 10; i++) din[i] = dint[(size_t)i * 2048 + g];
  const float* fr = feat + bi * 160;
  for (int cc = 0; cc < 16; cc++) {
    float acc = 0.0f;
#pragma unroll
    for (int i = 0; i < 10; i++) acc += fr[cc * 10 + i] * din[i];
    acc = fmaxf(acc, 0.0f) * 1.41421356237309505f;
    sig[(size_t)(bi * 16 + cc) * 2048 + g] = f2bf(acc);
  }
}

// ---------------------------------------------------------------------------
// K4: E_T [512][8192] bf16: row n=g*8+i, col k=f*512+jj
// ---------------------------------------------------------------------------
__global__ __launch_bounds__(256) void k_ebuild(W2Ptrs w2, const float* c8w,
                                                unsigned short* et, const int* flag) {
  int isf = __builtin_amdgcn_readfirstlane(flag[0]);
  int idx = blockIdx.x * 256 + threadIdx.x;     // 512*16*512
  int n = idx >> 13;
  int rest = idx & 8191;
  int f = rest >> 9, jj = rest & 511;
  size_t oaddr = (size_t)n * 8192 + f * 512 + jj;
  if (jj >= 455) { et[oaddr] = 0; return; }
  int l = 0;
  while (jj >= c_offs[l + 1]) l++;
  int d = 2 * l + 1;
  int rloc = jj - c_offs[l];
  int u = rloc / d, m = rloc % d;
  int g = n >> 3, i = n & 7;
  const void* wp = w2.p[l];
  float acc = 0.0f;
  for (int w = 0; w < d; w++) {
    float wv = in_val(wp, ((size_t)(f * 64 + g) * d + u) * d + w, isf);
    acc += wv * c8w[i * 512 + c_offs[l] + w * d + m];
  }
  acc *= rsqrtf((float)(16 * d));
  et[oaddr] = f2bf(acc);
}

// ---------------------------------------------------------------------------
// K5: GEMM2: f2[8192][512] = sig[8192][2048] @ dwt^T.
// BM=128 BN=64 BK=64, 32x32x16 MFMA, XOR-swizzled LDS (phys chunk = logical
// k-chunk ^ (row&7)) to break the 128B-stride bank aliasing.
// grid 512 = 64 mt x 8 nt; 4 waves: wm = wid>>1 (64 rows), wn = wid&1 (32 cols).
// ---------------------------------------------------------------------------
__global__ __launch_bounds__(256) void k_gemm2(const unsigned short* A,
                                               const unsigned short* B,
                                               unsigned short* C) {
  __shared__ __align__(16) unsigned short As[128 * 64];
  __shared__ __align__(16) unsigned short Bs[64 * 64];
  int tid = threadIdx.x;
  int lane = tid & 63, wid = tid >> 6;
  int mt = blockIdx.x >> 3, nt = blockIdx.x & 7;
  int m0 = mt * 128, n0 = nt * 64;
  int wm = wid >> 1, wn = wid & 1;
  f32x16 acc[2];
#pragma unroll
  for (int t = 0; t < 2; t++)
#pragma unroll
    for (int r = 0; r < 16; r++) acc[t][r] = 0.0f;

  // staging: chunk id within a 256-chunk issue = tid; row r0 = tid>>3,
  // phys chunk p = tid&7 holds logical kc = p ^ (r0&7).
  int r0 = tid >> 3;
  int kcl = (tid & 7) ^ (r0 & 7);          // logical k-chunk this lane fetches
  const unsigned short* Abase = A + (size_t)m0 * 2048;
  const unsigned short* Bbase = B + (size_t)n0 * 2048;
  // fragment read addressing
  int mrow = (lane & 31);                   // within 32-tile
  int xr = lane & 7;                        // row&7 for swizzle
  int khalf = lane >> 5;                    // 0/1 -> +8 k elems

  for (int kt = 0; kt < 32; kt++) {
    int k0 = kt * 64;
#pragma unroll
    for (int i = 0; i < 4; i++)
      gl_lds16(Abase + (size_t)(i * 32 + r0) * 2048 + k0 + kcl * 8,
               &As[i * 2048 + wid * 512]);
#pragma unroll
    for (int i = 0; i < 2; i++)
      gl_lds16(Bbase + (size_t)(i * 32 + r0) * 2048 + k0 + kcl * 8,
               &Bs[i * 2048 + wid * 512]);
    __syncthreads();
#pragma unroll
    for (int q = 0; q < 4; q++) {           // K quarters of 16
      int qc = q * 2 + khalf;               // logical k-chunk [0,8)
      bf16x8 bv = *(const bf16x8*)&Bs[(wn * 32 + mrow) * 64 + (qc ^ xr) * 8];
#pragma unroll
      for (int t = 0; t < 2; t++) {
        bf16x8 av = *(const bf16x8*)&As[(wm * 64 + t * 32 + mrow) * 64 + (qc ^ xr) * 8];
        acc[t] = __builtin_amdgcn_mfma_f32_32x32x16_bf16(av, bv, acc[t], 0, 0, 0);
      }
    }
    __syncthreads();
  }
  int col = n0 + wn * 32 + (lane & 31);
#pragma unroll
  for (int t = 0; t < 2; t++)
#pragma unroll
    for (int r = 0; r < 16; r++) {
      int row = m0 + wm * 64 + t * 32 + (r & 3) + 8 * (r >> 2) + 4 * (lane >> 5);
      C[(size_t)row * 512 + col] = f2bf(acc[t][r]);
    }
}

// ---------------------------------------------------------------------------
// K6: GEMM3 split-K=8: Cp[kc][512][512] f32 = f2[512][8192] @ E (E_T staged)
// ---------------------------------------------------------------------------
__global__ __launch_bounds__(256) void k_gemm3(const unsigned short* A,
                                               const unsigned short* B, float* Cp) {
  __shared__ __align__(16) unsigned short As[64 * 32];
  __shared__ __align__(16) unsigned short Bs[128 * 32];
  int tid = threadIdx.x, lane = tid & 63, wid = tid >> 6;
  int kc = blockIdx.x >> 5;
  int mt = (blockIdx.x >> 2) & 7, nt = blockIdx.x & 3;
  int m0 = mt * 64, n0 = nt * 128;
  int wm = wid >> 1, wn = wid & 1;
  f32x4 acc[2][4];
#pragma unroll
  for (int a = 0; a < 2; a++)
#pragma unroll
    for (int b = 0; b < 4; b++) acc[a][b] = (f32x4){0.f, 0.f, 0.f, 0.f};
  int c0 = tid;
  int ar = c0 >> 2, ak = (c0 & 3) * 8;
  const unsigned short* Abase = A + (size_t)m0 * 8192 + kc * 1024;
  const unsigned short* Bbase = B + (size_t)n0 * 8192 + kc * 1024;
  int row = lane & 15, kq = (lane >> 4) * 8;
  for (int kt = 0; kt < 32; kt++) {
    int k0 = kt * 32;
    gl_lds16(Abase + (size_t)ar * 8192 + k0 + ak, &As[wid * 512]);
    gl_lds16(Bbase + (size_t)ar * 8192 + k0 + ak, &Bs[wid * 512]);
    gl_lds16(Bbase + (size_t)(ar + 64) * 8192 + k0 + ak, &Bs[2048 + wid * 512]);
    __syncthreads();
    bf16x8 af[2], bfr[4];
#pragma unroll
    for (int im = 0; im < 2; im++)
      af[im] = *(const bf16x8*)&As[(wm * 32 + im * 16 + row) * 32 + kq];
#pragma unroll
    for (int in = 0; in < 4; in++)
      bfr[in] = *(const bf16x8*)&Bs[(wn * 64 + in * 16 + row) * 32 + kq];
#pragma unroll
    for (int im = 0; im < 2; im++)
#pragma unroll
      for (int in = 0; in < 4; in++)
        acc[im][in] = __builtin_amdgcn_mfma_f32_16x16x32_bf16(af[im], bfr[in],
                                                              acc[im][in], 0, 0, 0);
    __syncthreads();
  }
  int col = lane & 15, rq = (lane >> 4) * 4;
  float* out = Cp + (size_t)kc * 262144;
#pragma unroll
  for (int im = 0; im < 2; im++)
#pragma unroll
    for (int in = 0; in < 4; in++)
#pragma unroll
      for (int r = 0; r < 4; r++) {
        int rr = m0 + wm * 32 + im * 16 + rq + r;
        int cc = n0 + wn * 64 + in * 16 + col;
        out[(size_t)rr * 512 + cc] = acc[im][in][r];
      }
}

// ---------------------------------------------------------------------------
// K7: blocks [0,1024): x_c8 = x @ C8W^T (wave per 16 rows, shuffle reduce).
//     blocks [1024,1280): split-K reduce -> traj_c8.
// ---------------------------------------------------------------------------
__global__ __launch_bounds__(256) void k_xc8r(const void* x, const float* c8w,
                                              const float* Cp, void* dout,
                                              const int* flag) {
  int tid = threadIdx.x, lane = tid & 63, wid = tid >> 6;
  int isf = __builtin_amdgcn_readfirstlane(flag[0]);

  if (blockIdx.x >= 1024) {           // ---- split-K reduce ----
    int idx = (blockIdx.x - 1024) * 256 + tid;   // [0, 65536)
    const float4* c = (const float4*)Cp;
    float s0 = 0.f, s1 = 0.f, s2 = 0.f, s3 = 0.f;
#pragma unroll
    for (int p = 0; p < 8; p++) {
      float4 v = c[idx + p * 65536];
      s0 += v.x; s1 += v.y; s2 += v.z; s3 += v.w;
    }
    size_t base = 524288 + (size_t)idx * 4;
    if (isf) {
      float4 o; o.x = s0; o.y = s1; o.z = s2; o.w = s3;
      *(float4*)((float*)dout + base) = o;
    } else {
      unsigned int p0 = (unsigned int)f2bf(s0) | ((unsigned int)f2bf(s1) << 16);
      unsigned int p1 = (unsigned int)f2bf(s2) | ((unsigned int)f2bf(s3) << 16);
      uint2 pk; pk.x = p0; pk.y = p1;
      *(uint2*)((unsigned short*)dout + base) = pk;
    }
    return;
  }

  // ---- x_c8: wave per 16 rows, lane j covers col band, shuffle reduce ----
  int gw = blockIdx.x * 4 + wid;      // 4096 waves, 16 rows each
  float cw[8][8];
#pragma unroll
  for (int t = 0; t < 8; t++)
#pragma unroll
    for (int i = 0; i < 8; i++)
      cw[t][i] = c8w[i * 512 + t * 64 + lane];
  const float* xf = (const float*)x;
  const unsigned short* xh = (const unsigned short*)x;
  for (int r = gw * 16; r < gw * 16 + 16; r++) {
    float acc[8];
#pragma unroll
    for (int i = 0; i < 8; i++) acc[i] = 0.0f;
    if (isf) {
      const float* xr = xf + (size_t)r * 455;
#pragma unroll
      for (int t = 0; t < 8; t++) {
        int j = t * 64 + lane;
        float xv = (j < 455) ? xr[j] : 0.0f;
#pragma unroll
        for (int i = 0; i < 8; i++) acc[i] += xv * cw[t][i];
      }
    } else {
      const unsigned short* xr = xh + (size_t)r * 455;
#pragma unroll
      for (int t = 0; t < 8; t++) {
        int j = t * 64 + lane;
        float xv = (j < 455) ? bf2f(xr[j]) : 0.0f;
#pragma unroll
        for (int i = 0; i < 8; i++) acc[i] += xv * cw[t][i];
      }
    }
#pragma unroll
    for (int off = 32; off >= 1; off >>= 1)
#pragma unroll
      for (int i = 0; i < 8; i++) acc[i] += __shfl_xor(acc[i], off);
    float v = acc[0];
    v = (lane == 1) ? acc[1] : v;
    v = (lane == 2) ? acc[2] : v;
    v = (lane == 3) ? acc[3] : v;
    v = (lane == 4) ? acc[4] : v;
    v = (lane == 5) ? acc[5] : v;
    v = (lane == 6) ? acc[6] : v;
    v = (lane == 7) ? acc[7] : v;
    if (lane < 8) {
      if (isf) ((float*)dout)[(size_t)r * 8 + lane] = v;
      else     ((unsigned short*)dout)[(size_t)r * 8 + lane] = f2bf(v);
    }
  }
}

// ---------------------------------------------------------------------------
// host
// ---------------------------------------------------------------------------
extern "C" void kernel_launch(void* const* d_in, const int* in_sizes, int n_in,
                              void* d_out, int out_size, void* d_ws, size_t ws_size,
                              hipStream_t stream) {
  const void* x    = d_in[0];
  const void* traj = d_in[1];
  const void* w1l0 = d_in[2];
  const void* w1l1 = d_in[3];
  W2Ptrs w2;
  for (int l = 0; l < 7; l++) w2.p[l] = d_in[4 + l];

  char* ws = (char*)d_ws;
  double* exps          = (double*)(ws + 0);                 // 336*169*8
  float* dint           = (float*)(ws + 458752);             // 10*2048*4
  float* c8w            = (float*)(ws + 540672);             // 8*512*4
  unsigned short* dwt   = (unsigned short*)(ws + 573440);    // 512*2048*2
  float* feat           = (float*)(ws + 2670592);            // 512*160*4
  unsigned short* sig   = (unsigned short*)(ws + 2998272);   // 8192*2048*2
  unsigned short* f2    = (unsigned short*)(ws + 36552704);  // 8192*512*2
  unsigned short* et    = (unsigned short*)(ws + 44941312);  // 512*8192*2
  float* cp             = (float*)(ws + 53329920);           // 8*512*512*4
  int* flag             = (int*)(ws + 61718528);

  SetupArgs sa; QWArgs qa;
  for (int i = 0; i < 16; i++) sa.angA[i] = 2.0 * M_PI * (double)i / 16.0;
  static const double XB[8] = {
    -0.9602898564975363, -0.7966664774136267, -0.5255324099163290,
    -0.1834346424956498,  0.1834346424956498,  0.5255324099163290,
     0.7966664774136267,  0.9602898564975363};
  static const double WBv[8] = {
     0.1012285362903763, 0.2223810344533745, 0.3137066458778873,
     0.3626837833783620, 0.3626837833783620, 0.3137066458778873,
     0.2223810344533745, 0.1012285362903763};
  for (int i = 0; i < 8; i++) { sa.angB[i] = acos(XB[i]); qa.wb[i] = WBv[i]; }
  for (int i = 0; i < 8; i++) {
    double th = 2.0 * M_PI * (double)i / 8.0;
    double Mm[3][3] = {{cos(th), sin(th), 0.0},
                       {-sin(th), cos(th), 0.0},
                       {0.0, 0.0, 1.0}};
    double x0 = Mm[0][1], x1 = Mm[1][1], x2 = Mm[2][1];
    double bb = acos(fmax(-1.0, fmin(1.0, x1)));
    double aa = atan2(x0, x2);
    double ca_ = cos(aa), sa_ = sin(aa), cb_ = cos(bb), sb_ = sin(bb);
    double MY[3][3] = {{ca_, 0, sa_}, {0, 1, 0}, {-sa_, 0, ca_}};
    double MX[3][3] = {{1, 0, 0}, {0, cb_, -sb_}, {0, sb_, cb_}};
    double P1[3][3], Rr[3][3];
    for (int r = 0; r < 3; r++)
      for (int c = 0; c < 3; c++) {
        double s = 0.0;
        for (int k = 0; k < 3; k++) s += MY[r][k] * MX[k][c];
        P1[r][c] = s;
      }
    for (int r = 0; r < 3; r++)
      for (int c = 0; c < 3; c++) {
        double s = 0.0;
        for (int k = 0; k < 3; k++) s += P1[k][r] * Mm[k][c];  // P1^T @ M
        Rr[r][c] = s;
      }
    double gg = atan2(Rr[0][2], Rr[0][0]);
    sa.c8a[i] = aa; sa.c8b[i] = bb; sa.c8g[i] = gg;
  }

  k_exps<<<337, 64, 0, stream>>>(sa, exps, x, flag);
  k_assemble<<<4920, 64, 0, stream>>>(exps, qa, dwt, dint, c8w,
                                      traj, w1l0, w1l1, feat, flag);
  k_sig<<<4096, 256, 0, stream>>>(feat, dint, sig);
  k_ebuild<<<16384, 256, 0, stream>>>(w2, c8w, et, flag);
  k_gemm2<<<512, 256, 0, stream>>>(sig, dwt, f2);
  k_gemm3<<<256, 256, 0, stream>>>(f2, et, cp);
  k_xc8r<<<1280, 256, 0, stream>>>(x, c8w, cp, d_out, flag);
}